// Round 7
// baseline (356.357 us; speedup 1.0000x reference)
//
#include <hip/hip_runtime.h>
#include <hip/hip_bf16.h>

// GCN 4-layer, N=50000, E=800000, dims 100->512->256->128->200.
// f16 MFMA GEMMs (128x128 tile) with ALL global activations in fp8 e4m3
// (decode-in-staging); weights f16 (no systematic error); fp32 accumulate.
// CSR build: 4 edges/thread for MLP on the atomic->scatter chain.

#define NN 50000
#define NE 800000

typedef __attribute__((ext_vector_type(8))) _Float16 f16x8;
typedef __attribute__((ext_vector_type(4))) float floatx4;
typedef __attribute__((ext_vector_type(2))) float floatx2;

union U16x8 {
    uint4 u4;
    f16x8 h;
    _Float16 e[8];
};

// decode 16 fp8 (16 B) -> 16 fp32 via HW cvt
__device__ __forceinline__ void dec16(const unsigned char* p, float* f) {
    uint4 v = *(const uint4*)p;
    unsigned w[4] = {v.x, v.y, v.z, v.w};
#pragma unroll
    for (int k = 0; k < 4; k++) {
        floatx2 lo = __builtin_amdgcn_cvt_pk_f32_fp8(w[k], false);
        floatx2 hi = __builtin_amdgcn_cvt_pk_f32_fp8(w[k], true);
        f[k * 4 + 0] = lo[0];
        f[k * 4 + 1] = lo[1];
        f[k * 4 + 2] = hi[0];
        f[k * 4 + 3] = hi[1];
    }
}

// encode 16 fp32 -> 16 fp8 (16 B)
__device__ __forceinline__ uint4 enc16(const float* f) {
    uint4 r;
    unsigned w;
    w = __builtin_amdgcn_cvt_pk_fp8_f32(f[0], f[1], 0, false);
    w = __builtin_amdgcn_cvt_pk_fp8_f32(f[2], f[3], (int)w, true);
    r.x = w;
    w = __builtin_amdgcn_cvt_pk_fp8_f32(f[4], f[5], 0, false);
    w = __builtin_amdgcn_cvt_pk_fp8_f32(f[6], f[7], (int)w, true);
    r.y = w;
    w = __builtin_amdgcn_cvt_pk_fp8_f32(f[8], f[9], 0, false);
    w = __builtin_amdgcn_cvt_pk_fp8_f32(f[10], f[11], (int)w, true);
    r.z = w;
    w = __builtin_amdgcn_cvt_pk_fp8_f32(f[12], f[13], 0, false);
    w = __builtin_amdgcn_cvt_pk_fp8_f32(f[14], f[15], (int)w, true);
    r.w = w;
    return r;
}

// decode 8 fp8 (8 B) -> 8 f16
__device__ __forceinline__ uint4 dec8_f16(uint2 v) {
    floatx2 f0 = __builtin_amdgcn_cvt_pk_f32_fp8(v.x, false);
    floatx2 f1 = __builtin_amdgcn_cvt_pk_f32_fp8(v.x, true);
    floatx2 f2 = __builtin_amdgcn_cvt_pk_f32_fp8(v.y, false);
    floatx2 f3 = __builtin_amdgcn_cvt_pk_f32_fp8(v.y, true);
    U16x8 o;
    o.e[0] = (_Float16)f0[0]; o.e[1] = (_Float16)f0[1];
    o.e[2] = (_Float16)f1[0]; o.e[3] = (_Float16)f1[1];
    o.e[4] = (_Float16)f2[0]; o.e[5] = (_Float16)f2[1];
    o.e[6] = (_Float16)f3[0]; o.e[7] = (_Float16)f3[1];
    return o.u4;
}

// ---------------- fused zero + dtype-detect ----------------
__global__ __launch_bounds__(256) void zero_detect_kernel(
    const unsigned* __restrict__ ei, int* __restrict__ flag,
    unsigned* __restrict__ cnt, unsigned* __restrict__ fillc,
    float* __restrict__ out) {
    int tid = blockIdx.x * 256 + threadIdx.x;
    if (tid < NN) {
        cnt[tid] = 0u;
        fillc[tid] = 0u;
    }
    if (blockIdx.x == 0) {
        if (threadIdx.x < 200) out[threadIdx.x] = 0.f;
        // int64 little-endian values < 2^31 => every odd 32-bit word == 0
        unsigned w = ei[2 * threadIdx.x + 1];
        unsigned long long any = __ballot(w != 0);
        if (threadIdx.x == 0) *flag = (any == 0ull) ? 1 : 0;
    }
}

// 4 edges per thread: independent atomic chains for MLP
__global__ __launch_bounds__(256) void count_kernel(const void* ei,
                                                    const int* __restrict__ flag,
                                                    unsigned* __restrict__ cnt) {
    int base = (blockIdx.x * 256 + threadIdx.x) * 4;
    if (base >= NE) return;
    int c[4];
    if (*flag) {
        const long long* p = (const long long*)ei + NE;
#pragma unroll
        for (int i = 0; i < 4; i++) c[i] = (int)p[base + i];
    } else {
        const int* p = (const int*)ei + NE;
#pragma unroll
        for (int i = 0; i < 4; i++) c[i] = p[base + i];
    }
#pragma unroll
    for (int i = 0; i < 4; i++) atomicAdd(&cnt[c[i]], 1u);
}

// hierarchical scan step 1 (49 blocks x 1024 elems) + fused dinv
__global__ __launch_bounds__(256) void scan1_kernel(const unsigned* __restrict__ cnt,
                                                    int* __restrict__ off,
                                                    int* __restrict__ bsum,
                                                    float* __restrict__ dinv) {
    __shared__ int ws[4];
    int b = blockIdx.x, t = threadIdx.x;
    int base = b * 1024 + t * 4;
    int v[4];
    int s = 0;
#pragma unroll
    for (int i = 0; i < 4; i++) {
        int val = 0;
        if (base + i < NN) {
            val = (int)cnt[base + i];
            dinv[base + i] = rsqrtf((float)(val + 1));
        }
        v[i] = s;
        s += val;
    }
    int lane = t & 63, wv = t >> 6;
    int x = s;
    for (int d = 1; d < 64; d <<= 1) {
        int y = __shfl_up(x, d, 64);
        if (lane >= d) x += y;
    }
    if (lane == 63) ws[wv] = x;
    __syncthreads();
    int wpre = 0;
#pragma unroll
    for (int i = 0; i < 4; i++)
        if (i < wv) wpre += ws[i];
    int texcl = x - s + wpre;
#pragma unroll
    for (int i = 0; i < 4; i++)
        if (base + i < NN) off[base + i] = texcl + v[i];
    if (t == 255) bsum[b] = texcl + s;
}

__global__ void scan2_kernel(int* bsum, int nb) {
    int t = threadIdx.x;
    int v = (t < nb) ? bsum[t] : 0;
    int x = v;
    for (int d = 1; d < 64; d <<= 1) {
        int y = __shfl_up(x, d, 64);
        if (t >= d) x += y;
    }
    if (t < nb) bsum[t] = x - v;
}

__global__ __launch_bounds__(256) void scan3_kernel(int* __restrict__ off,
                                                    const int* __restrict__ bsum) {
    int b = blockIdx.x;
    int add = bsum[b];
    int base = b * 1024 + threadIdx.x * 4;
#pragma unroll
    for (int i = 0; i < 4; i++)
        if (base + i < NN) off[base + i] += add;
    if (b == 0 && threadIdx.x == 0) off[NN] = NE;
}

// fill CSR, 4 edges/thread: ep[pos] = {src_row, bitcast(norm)}
__global__ __launch_bounds__(256) void fill_kernel(
    const void* ei, const int* __restrict__ flag, const int* __restrict__ off,
    unsigned* __restrict__ fillc, const float* __restrict__ dinv,
    int2* __restrict__ ep) {
    int base = (blockIdx.x * 256 + threadIdx.x) * 4;
    if (base >= NE) return;
    int r[4], c[4];
    if (*flag) {
        const long long* p = (const long long*)ei;
#pragma unroll
        for (int i = 0; i < 4; i++) {
            r[i] = (int)p[base + i];
            c[i] = (int)p[NE + base + i];
        }
    } else {
        const int* p = (const int*)ei;
#pragma unroll
        for (int i = 0; i < 4; i++) {
            r[i] = p[base + i];
            c[i] = p[NE + base + i];
        }
    }
    int pos[4];
#pragma unroll
    for (int i = 0; i < 4; i++)
        pos[i] = off[c[i]] + (int)atomicAdd(&fillc[c[i]], 1u);
#pragma unroll
    for (int i = 0; i < 4; i++) {
        int2 v;
        v.x = r[i];
        v.y = __float_as_int(dinv[r[i]] * dinv[c[i]]);
        ep[pos[i]] = v;
    }
}

// fused: x fp32 [NN,100] -> fp8 [NN,128] zero-padded (blocks 0..1562)
//      + all 4 weights W [K,N] fp32 -> Wt [Npad,Kpad] f16 (blocks 1563..2586)
__global__ __launch_bounds__(256) void xwcast_kernel(
    const float* __restrict__ x, unsigned char* __restrict__ xb,
    const float* __restrict__ W1, const float* __restrict__ W2,
    const float* __restrict__ W3, const float* __restrict__ W4,
    _Float16* __restrict__ w1t, _Float16* __restrict__ w2t,
    _Float16* __restrict__ w3t, _Float16* __restrict__ w4t) {
    int bx = blockIdx.x, t = threadIdx.x;
    if (bx < 1563) {
        int tid = bx * 256 + t;
        int node = tid >> 3, sub = tid & 7;
        if (node >= NN) return;
        int base = sub * 16;
        float f[16];
#pragma unroll
        for (int i = 0; i < 16; i++) {
            int c = base + i;
            f[i] = (c < 100) ? x[(size_t)node * 100 + c] : 0.f;
        }
        *(uint4*)(xb + (size_t)node * 128 + base) = enc16(f);
        return;
    }
    int b = bx - 1563;
    const float* W;
    _Float16* Wt;
    int K, N, Kpad, tid;
    if (b < 256)      { W = W1; Wt = w1t; K = 100; N = 512; Kpad = 128; tid = b * 256 + t; }
    else if (b < 768) { W = W2; Wt = w2t; K = 512; N = 256; Kpad = 512; tid = (b - 256) * 256 + t; }
    else if (b < 896) { W = W3; Wt = w3t; K = 256; N = 128; Kpad = 256; tid = (b - 768) * 256 + t; }
    else              { W = W4; Wt = w4t; K = 128; N = 200; Kpad = 128; tid = (b - 896) * 256 + t; }
    int n = tid / Kpad, k = tid - n * Kpad;
    float v = (k < K && n < N) ? W[(size_t)k * N + n] : 0.f;
    Wt[tid] = (_Float16)v;
}

// aggregation: fp8 gathers + fp8 output, fp32 accumulate.
// D/16 lanes per node (16 feat/lane). BR=1: bias+relu epilogue.
template <int D, int BR>
__global__ __launch_bounds__(256) void agg_kernel(
    const unsigned char* __restrict__ H, const int* __restrict__ off,
    const int2* __restrict__ ep, const float* __restrict__ dinv,
    const float* __restrict__ bias, unsigned char* __restrict__ O) {
    constexpr int LPN = D / 16;
    int tid = blockIdx.x * 256 + threadIdx.x;
    int node = tid / LPN;
    int sub = tid % LPN;
    if (node >= NN) return;
    int s = off[node], e = off[node + 1];
    float dc = dinv[node];
    float selfw = dc * dc;
    const int base = sub * 16;
    const unsigned char* __restrict__ Hb = H + base;
    float acc[16], t0[16], t1[16];
    dec16(Hb + (size_t)node * D, t0);
#pragma unroll
    for (int i = 0; i < 16; i++) acc[i] = selfw * t0[i];
    int j = s;
    for (; j + 2 <= e; j += 2) {
        int2 q0 = ep[j];
        int2 q1 = ep[j + 1];
        dec16(Hb + (size_t)q0.x * D, t0);
        dec16(Hb + (size_t)q1.x * D, t1);
        float w0 = __int_as_float(q0.y);
        float w1 = __int_as_float(q1.y);
#pragma unroll
        for (int i = 0; i < 16; i++) acc[i] = fmaf(w0, t0[i], acc[i]);
#pragma unroll
        for (int i = 0; i < 16; i++) acc[i] = fmaf(w1, t1[i], acc[i]);
    }
    if (j < e) {
        int2 q0 = ep[j];
        dec16(Hb + (size_t)q0.x * D, t0);
        float w0 = __int_as_float(q0.y);
#pragma unroll
        for (int i = 0; i < 16; i++) acc[i] = fmaf(w0, t0[i], acc[i]);
    }
    if (BR) {
#pragma unroll
        for (int i = 0; i < 16; i++) acc[i] = fmaxf(acc[i] + bias[base + i], 0.f);
    }
    *(uint4*)(O + (size_t)node * D + base) = enc16(acc);
}

// MFMA GEMM: C[M,N] = A[M,K] @ B^T; A is fp8 [M,K] (decoded to f16 in LDS
// staging), B is [Npad,K] f16. 128x128 tile, 256 threads (2x2 waves of 64x64),
// 16x16x32 f16 MFMA. LDS row stride 40 elems to break 8-way bank aliasing.
// EPI: 0 = fp8 store, 1 = bias+relu fp8 store, 2 = bias+relu+column-mean atomic.
template <int EPI>
__global__ __launch_bounds__(256) void gemm_kernel(
    const unsigned char* __restrict__ A, const _Float16* __restrict__ B,
    const float* __restrict__ bias, unsigned char* __restrict__ Cb,
    float* __restrict__ outmean, int M, int K, int N) {
    __shared__ _Float16 Asl[128 * 40];
    __shared__ _Float16 Bsl[128 * 40];
    __shared__ float red[128];
    const int m0 = blockIdx.y * 128;
    const int n0 = blockIdx.x * 128;
    const int t = threadIdx.x;
    const int lane = t & 63, w = t >> 6;
    const int wm = (w >> 1) * 64, wn = (w & 1) * 64;
    const int r16 = lane & 15, quad = lane >> 4;

    floatx4 acc[4][4];
    const floatx4 fz = {0.f, 0.f, 0.f, 0.f};
#pragma unroll
    for (int i = 0; i < 4; i++)
#pragma unroll
        for (int j = 0; j < 4; j++) acc[i][j] = fz;

    for (int kc = 0; kc < K; kc += 32) {
        __syncthreads();
#pragma unroll
        for (int i = 0; i < 2; i++) {
            int seg = t + 256 * i;
            int row = seg >> 2, k8 = (seg & 3) * 8;
            int gm = m0 + row;
            if (gm > M - 1) gm = M - 1;
            uint2 av = *(const uint2*)(A + (size_t)gm * K + kc + k8);
            *(uint4*)(Asl + row * 40 + k8) = dec8_f16(av);
            int gn = n0 + row;  // B padded to Npad multiple of 128
            *(uint4*)(Bsl + row * 40 + k8) = *(const uint4*)(B + (size_t)gn * K + kc + k8);
        }
        __syncthreads();
        f16x8 af[4], bf[4];
#pragma unroll
        for (int i = 0; i < 4; i++)
            af[i] = *(const f16x8*)(Asl + (wm + i * 16 + r16) * 40 + quad * 8);
#pragma unroll
        for (int j = 0; j < 4; j++)
            bf[j] = *(const f16x8*)(Bsl + (wn + j * 16 + r16) * 40 + quad * 8);
#pragma unroll
        for (int i = 0; i < 4; i++)
#pragma unroll
            for (int j = 0; j < 4; j++)
                acc[i][j] = __builtin_amdgcn_mfma_f32_16x16x32_f16(af[i], bf[j], acc[i][j], 0, 0, 0);
    }

    if (EPI == 2) {
        if (t < 128) red[t] = 0.f;
        __syncthreads();
#pragma unroll
        for (int j = 0; j < 4; j++) {
            int col = n0 + wn + j * 16 + r16;
            float s = 0.f;
            if (col < N) {
                float bv = bias[col];
#pragma unroll
                for (int i = 0; i < 4; i++)
#pragma unroll
                    for (int r = 0; r < 4; r++) {
                        int m = m0 + wm + i * 16 + quad * 4 + r;
                        if (m < M) s += fmaxf(acc[i][j][r] + bv, 0.f);
                    }
            }
            atomicAdd(&red[wn + j * 16 + r16], s);
        }
        __syncthreads();
        if (t < 128) {
            int col = n0 + t;
            if (col < N) atomicAdd(outmean + col, red[t] * (1.0f / (float)NN));
        }
    } else {
#pragma unroll
        for (int i = 0; i < 4; i++)
#pragma unroll
            for (int r = 0; r < 4; r++) {
                int m = m0 + wm + i * 16 + quad * 4 + r;
                if (m >= M) continue;
#pragma unroll
                for (int j = 0; j < 4; j++) {
                    int col = n0 + wn + j * 16 + r16;
                    float v = acc[i][j][r];
                    if (EPI == 1) v = fmaxf(v + bias[col], 0.f);
                    unsigned pk = __builtin_amdgcn_cvt_pk_fp8_f32(v, v, 0, false);
                    Cb[(size_t)m * N + col] = (unsigned char)(pk & 0xffu);
                }
            }
    }
}

extern "C" void kernel_launch(void* const* d_in, const int* in_sizes, int n_in,
                              void* d_out, int out_size, void* d_ws, size_t ws_size,
                              hipStream_t stream) {
    const float* x  = (const float*)d_in[0];
    const void*  ei = d_in[1];
    const float* W1 = (const float*)d_in[2];
    const float* b1 = (const float*)d_in[3];
    const float* W2 = (const float*)d_in[4];
    const float* b2 = (const float*)d_in[5];
    const float* W3 = (const float*)d_in[6];
    const float* b3 = (const float*)d_in[7];
    const float* W4 = (const float*)d_in[8];
    const float* b4 = (const float*)d_in[9];
    float* out = (float*)d_out;

    char* ws = (char*)d_ws;
    size_t o = 0;
    auto alloc = [&](size_t bytes) -> void* {
        void* p = ws + o;
        o += (bytes + 255) & ~(size_t)255;
        return p;
    };
    int*      flag  = (int*)alloc(4);
    unsigned* cnt   = (unsigned*)alloc((size_t)NN * 4);
    int*      off   = (int*)alloc((size_t)(NN + 1) * 4);
    unsigned* fillc = (unsigned*)alloc((size_t)NN * 4);
    float*    dinv  = (float*)alloc((size_t)NN * 4);
    int2*     ep    = (int2*)alloc((size_t)NE * 8);
    _Float16* w1t = (_Float16*)alloc((size_t)512 * 128 * 2);
    _Float16* w2t = (_Float16*)alloc((size_t)256 * 512 * 2);
    _Float16* w3t = (_Float16*)alloc((size_t)128 * 256 * 2);
    _Float16* w4t = (_Float16*)alloc((size_t)256 * 128 * 2);
    int*      bsum  = (int*)alloc(256);
    // all activation buffers fp8 e4m3
    unsigned char* xb  = (unsigned char*)alloc((size_t)NN * 128);
    unsigned char* A1b = (unsigned char*)alloc((size_t)NN * 128);
    unsigned char* H1b = (unsigned char*)alloc((size_t)NN * 512);
    unsigned char* t2b = (unsigned char*)alloc((size_t)NN * 256);
    unsigned char* H2b = (unsigned char*)alloc((size_t)NN * 256);
    unsigned char* t3b = (unsigned char*)alloc((size_t)NN * 128);
    unsigned char* h3b = (unsigned char*)alloc((size_t)NN * 128);
    unsigned char* A4b = (unsigned char*)alloc((size_t)NN * 128);

    const int EB4 = (NE / 4 + 255) / 256;  // 782 (4 edges/thread)
    const int NB1 = (NN + 1023) / 1024;    // 49
    const int ZB = (NN + 255) / 256;       // 196

    zero_detect_kernel<<<ZB, 256, 0, stream>>>((const unsigned*)ei, flag, cnt, fillc, out);
    count_kernel<<<EB4, 256, 0, stream>>>(ei, flag, cnt);
    scan1_kernel<<<NB1, 256, 0, stream>>>(cnt, off, bsum, dinv);
    scan2_kernel<<<1, 64, 0, stream>>>(bsum, NB1);
    scan3_kernel<<<NB1, 256, 0, stream>>>(off, bsum);
    fill_kernel<<<EB4, 256, 0, stream>>>(ei, flag, off, fillc, dinv, ep);
    xwcast_kernel<<<1563 + 1024, 256, 0, stream>>>(x, xb, W1, W2, W3, W4, w1t, w2t, w3t, w4t);

    const int MB = (NN + 127) / 128;         // 391
    const int AB128 = (NN * 8 + 255) / 256;  // 1563 (D=128: 8 lanes/node)
    const int AB256 = (NN * 16 + 255) / 256; // 3125 (D=256: 16 lanes/node)

    // L1: agg(xb) -> A1; gemm + bias + relu -> H1 [NN,512]
    agg_kernel<128, 0><<<AB128, 256, 0, stream>>>(xb, off, ep, dinv, nullptr, A1b);
    gemm_kernel<1><<<dim3(4, MB), 256, 0, stream>>>(A1b, w1t, b1, H1b, nullptr, NN, 128, 512);
    // L2: gemm H1 -> t2 [NN,256]; agg + bias + relu -> H2
    gemm_kernel<0><<<dim3(2, MB), 256, 0, stream>>>(H1b, w2t, nullptr, t2b, nullptr, NN, 512, 256);
    agg_kernel<256, 1><<<AB256, 256, 0, stream>>>(t2b, off, ep, dinv, b2, H2b);
    // L3: gemm H2 -> t3 [NN,128]; agg + bias + relu -> h3
    gemm_kernel<0><<<dim3(1, MB), 256, 0, stream>>>(H2b, w3t, nullptr, t3b, nullptr, NN, 256, 128);
    agg_kernel<128, 1><<<AB128, 256, 0, stream>>>(t3b, off, ep, dinv, b3, h3b);
    // L4: agg(h3) -> A4; gemm + bias + relu + fused column mean -> out
    agg_kernel<128, 0><<<AB128, 256, 0, stream>>>(h3b, off, ep, dinv, nullptr, A4b);
    gemm_kernel<2><<<dim3(2, MB), 256, 0, stream>>>(A4b, w4t, b4, nullptr, out, NN, 128, 200);
}

// Round 8
// 354.223 us; speedup vs baseline: 1.0060x; 1.0060x over previous
//
#include <hip/hip_runtime.h>
#include <hip/hip_bf16.h>

// GCN 4-layer, N=50000, E=800000, dims 100->512->256->128->200.
// f16 MFMA GEMMs (128x128 tile), ALL global activations fp8 e4m3
// (decode-in-staging), weights f16, fp32 accumulate.
// CSR build XCD-partitioned (blockIdx&7 owns a node range) to kill the
// 8x cross-XCD write amplification seen in r7 (WRITE_SIZE 53MB for 6.4MB ep).
// ep stores src row only (4B); norm recomputed in agg from dinv (bit-identical).

#define NN 50000
#define NE 800000
#define NPART 8
#define PRANGE (NN / NPART)  // 6250

typedef __attribute__((ext_vector_type(8))) _Float16 f16x8;
typedef __attribute__((ext_vector_type(4))) float floatx4;
typedef __attribute__((ext_vector_type(2))) float floatx2;

union U16x8 {
    uint4 u4;
    f16x8 h;
    _Float16 e[8];
};

// decode 16 fp8 (16 B) -> 16 fp32 via HW cvt
__device__ __forceinline__ void dec16(const unsigned char* p, float* f) {
    uint4 v = *(const uint4*)p;
    unsigned w[4] = {v.x, v.y, v.z, v.w};
#pragma unroll
    for (int k = 0; k < 4; k++) {
        floatx2 lo = __builtin_amdgcn_cvt_pk_f32_fp8(w[k], false);
        floatx2 hi = __builtin_amdgcn_cvt_pk_f32_fp8(w[k], true);
        f[k * 4 + 0] = lo[0];
        f[k * 4 + 1] = lo[1];
        f[k * 4 + 2] = hi[0];
        f[k * 4 + 3] = hi[1];
    }
}

// encode 16 fp32 -> 16 fp8 (16 B)
__device__ __forceinline__ uint4 enc16(const float* f) {
    uint4 r;
    unsigned w;
    w = __builtin_amdgcn_cvt_pk_fp8_f32(f[0], f[1], 0, false);
    w = __builtin_amdgcn_cvt_pk_fp8_f32(f[2], f[3], (int)w, true);
    r.x = w;
    w = __builtin_amdgcn_cvt_pk_fp8_f32(f[4], f[5], 0, false);
    w = __builtin_amdgcn_cvt_pk_fp8_f32(f[6], f[7], (int)w, true);
    r.y = w;
    w = __builtin_amdgcn_cvt_pk_fp8_f32(f[8], f[9], 0, false);
    w = __builtin_amdgcn_cvt_pk_fp8_f32(f[10], f[11], (int)w, true);
    r.z = w;
    w = __builtin_amdgcn_cvt_pk_fp8_f32(f[12], f[13], 0, false);
    w = __builtin_amdgcn_cvt_pk_fp8_f32(f[14], f[15], (int)w, true);
    r.w = w;
    return r;
}

// decode 8 fp8 (8 B) -> 8 f16
__device__ __forceinline__ uint4 dec8_f16(uint2 v) {
    floatx2 f0 = __builtin_amdgcn_cvt_pk_f32_fp8(v.x, false);
    floatx2 f1 = __builtin_amdgcn_cvt_pk_f32_fp8(v.x, true);
    floatx2 f2 = __builtin_amdgcn_cvt_pk_f32_fp8(v.y, false);
    floatx2 f3 = __builtin_amdgcn_cvt_pk_f32_fp8(v.y, true);
    U16x8 o;
    o.e[0] = (_Float16)f0[0]; o.e[1] = (_Float16)f0[1];
    o.e[2] = (_Float16)f1[0]; o.e[3] = (_Float16)f1[1];
    o.e[4] = (_Float16)f2[0]; o.e[5] = (_Float16)f2[1];
    o.e[6] = (_Float16)f3[0]; o.e[7] = (_Float16)f3[1];
    return o.u4;
}

// ---------------- fused zero + dtype-detect ----------------
__global__ __launch_bounds__(256) void zero_detect_kernel(
    const unsigned* __restrict__ ei, int* __restrict__ flag,
    unsigned* __restrict__ cnt, unsigned* __restrict__ fillc,
    float* __restrict__ out) {
    int tid = blockIdx.x * 256 + threadIdx.x;
    if (tid < NN) {
        cnt[tid] = 0u;
        fillc[tid] = 0u;
    }
    if (blockIdx.x == 0) {
        if (threadIdx.x < 200) out[threadIdx.x] = 0.f;
        // int64 little-endian values < 2^31 => every odd 32-bit word == 0
        unsigned w = ei[2 * threadIdx.x + 1];
        unsigned long long any = __ballot(w != 0);
        if (threadIdx.x == 0) *flag = (any == 0ull) ? 1 : 0;
    }
}

// XCD-partitioned count: partition (blockIdx&7) owns c in [p*6250,(p+1)*6250).
// All partitions stream the whole c-array (L3-served re-reads); atomics and
// cnt lines stay single-partition -> no cross-XCD line bouncing.
__global__ __launch_bounds__(256) void count_kernel(const void* ei,
                                                    const int* __restrict__ flag,
                                                    unsigned* __restrict__ cnt) {
    const int part = blockIdx.x & 7;
    const int lo = part * PRANGE, hi = lo + PRANGE;
    const int group = blockIdx.x >> 3;           // 0..127
    const int f64 = *flag;
    const long long* p64 = (const long long*)ei + NE;
    const int* p32 = (const int*)ei + NE;
    for (int e = group * 256 + threadIdx.x; e < NE; e += 128 * 256) {
        int c = f64 ? (int)p64[e] : p32[e];
        if (c >= lo && c < hi) atomicAdd(&cnt[c], 1u);
    }
}

// hierarchical scan step 1 (49 blocks x 1024 elems) + fused dinv
__global__ __launch_bounds__(256) void scan1_kernel(const unsigned* __restrict__ cnt,
                                                    int* __restrict__ off,
                                                    int* __restrict__ bsum,
                                                    float* __restrict__ dinv) {
    __shared__ int ws[4];
    int b = blockIdx.x, t = threadIdx.x;
    int base = b * 1024 + t * 4;
    int v[4];
    int s = 0;
#pragma unroll
    for (int i = 0; i < 4; i++) {
        int val = 0;
        if (base + i < NN) {
            val = (int)cnt[base + i];
            dinv[base + i] = rsqrtf((float)(val + 1));
        }
        v[i] = s;
        s += val;
    }
    int lane = t & 63, wv = t >> 6;
    int x = s;
    for (int d = 1; d < 64; d <<= 1) {
        int y = __shfl_up(x, d, 64);
        if (lane >= d) x += y;
    }
    if (lane == 63) ws[wv] = x;
    __syncthreads();
    int wpre = 0;
#pragma unroll
    for (int i = 0; i < 4; i++)
        if (i < wv) wpre += ws[i];
    int texcl = x - s + wpre;
#pragma unroll
    for (int i = 0; i < 4; i++)
        if (base + i < NN) off[base + i] = texcl + v[i];
    if (t == 255) bsum[b] = texcl + s;
}

__global__ void scan2_kernel(int* bsum, int nb) {
    int t = threadIdx.x;
    int v = (t < nb) ? bsum[t] : 0;
    int x = v;
    for (int d = 1; d < 64; d <<= 1) {
        int y = __shfl_up(x, d, 64);
        if (t >= d) x += y;
    }
    if (t < nb) bsum[t] = x - v;
}

__global__ __launch_bounds__(256) void scan3_kernel(int* __restrict__ off,
                                                    const int* __restrict__ bsum) {
    int b = blockIdx.x;
    int add = bsum[b];
    int base = b * 1024 + threadIdx.x * 4;
#pragma unroll
    for (int i = 0; i < 4; i++)
        if (base + i < NN) off[base + i] += add;
    if (b == 0 && threadIdx.x == 0) off[NN] = NE;
}

// XCD-partitioned fill: ep[pos] = src row (4B). norm recomputed in agg.
__global__ __launch_bounds__(256) void fill_kernel(
    const void* ei, const int* __restrict__ flag, const int* __restrict__ off,
    unsigned* __restrict__ fillc, int* __restrict__ ep) {
    const int part = blockIdx.x & 7;
    const int lo = part * PRANGE, hi = lo + PRANGE;
    const int group = blockIdx.x >> 3;
    const int f64 = *flag;
    const long long* p64 = (const long long*)ei;
    const int* p32 = (const int*)ei;
    for (int e = group * 256 + threadIdx.x; e < NE; e += 128 * 256) {
        int c = f64 ? (int)p64[NE + e] : p32[NE + e];
        if (c >= lo && c < hi) {
            int r = f64 ? (int)p64[e] : p32[e];
            int pos = off[c] + (int)atomicAdd(&fillc[c], 1u);
            ep[pos] = r;
        }
    }
}

// fused: x fp32 [NN,100] -> fp8 [NN,128] zero-padded (blocks 0..1562)
//      + all 4 weights W [K,N] fp32 -> Wt [Npad,Kpad] f16 (blocks 1563..2586)
__global__ __launch_bounds__(256) void xwcast_kernel(
    const float* __restrict__ x, unsigned char* __restrict__ xb,
    const float* __restrict__ W1, const float* __restrict__ W2,
    const float* __restrict__ W3, const float* __restrict__ W4,
    _Float16* __restrict__ w1t, _Float16* __restrict__ w2t,
    _Float16* __restrict__ w3t, _Float16* __restrict__ w4t) {
    int bx = blockIdx.x, t = threadIdx.x;
    if (bx < 1563) {
        int tid = bx * 256 + t;
        int node = tid >> 3, sub = tid & 7;
        if (node >= NN) return;
        int base = sub * 16;
        float f[16];
#pragma unroll
        for (int i = 0; i < 16; i++) {
            int c = base + i;
            f[i] = (c < 100) ? x[(size_t)node * 100 + c] : 0.f;
        }
        *(uint4*)(xb + (size_t)node * 128 + base) = enc16(f);
        return;
    }
    int b = bx - 1563;
    const float* W;
    _Float16* Wt;
    int K, N, Kpad, tid;
    if (b < 256)      { W = W1; Wt = w1t; K = 100; N = 512; Kpad = 128; tid = b * 256 + t; }
    else if (b < 768) { W = W2; Wt = w2t; K = 512; N = 256; Kpad = 512; tid = (b - 256) * 256 + t; }
    else if (b < 896) { W = W3; Wt = w3t; K = 256; N = 128; Kpad = 256; tid = (b - 768) * 256 + t; }
    else              { W = W4; Wt = w4t; K = 128; N = 200; Kpad = 128; tid = (b - 896) * 256 + t; }
    int n = tid / Kpad, k = tid - n * Kpad;
    float v = (k < K && n < N) ? W[(size_t)k * N + n] : 0.f;
    Wt[tid] = (_Float16)v;
}

// aggregation: fp8 gathers + fp8 output, fp32 accumulate.
// D/16 lanes per node (16 feat/lane). norm = dinv[r]*dinv[c] recomputed
// (dinv is 200KB -> L2-resident; load overlaps the feature gather).
template <int D, int BR>
__global__ __launch_bounds__(256) void agg_kernel(
    const unsigned char* __restrict__ H, const int* __restrict__ off,
    const int* __restrict__ ep, const float* __restrict__ dinv,
    const float* __restrict__ bias, unsigned char* __restrict__ O) {
    constexpr int LPN = D / 16;
    int tid = blockIdx.x * 256 + threadIdx.x;
    int node = tid / LPN;
    int sub = tid % LPN;
    if (node >= NN) return;
    int s = off[node], e = off[node + 1];
    float dc = dinv[node];
    float selfw = dc * dc;
    const int base = sub * 16;
    const unsigned char* __restrict__ Hb = H + base;
    float acc[16], t0[16], t1[16];
    dec16(Hb + (size_t)node * D, t0);
#pragma unroll
    for (int i = 0; i < 16; i++) acc[i] = selfw * t0[i];
    int j = s;
    for (; j + 2 <= e; j += 2) {
        int r0 = ep[j];
        int r1 = ep[j + 1];
        float w0 = dinv[r0] * dc;
        float w1 = dinv[r1] * dc;
        dec16(Hb + (size_t)r0 * D, t0);
        dec16(Hb + (size_t)r1 * D, t1);
#pragma unroll
        for (int i = 0; i < 16; i++) acc[i] = fmaf(w0, t0[i], acc[i]);
#pragma unroll
        for (int i = 0; i < 16; i++) acc[i] = fmaf(w1, t1[i], acc[i]);
    }
    if (j < e) {
        int r0 = ep[j];
        float w0 = dinv[r0] * dc;
        dec16(Hb + (size_t)r0 * D, t0);
#pragma unroll
        for (int i = 0; i < 16; i++) acc[i] = fmaf(w0, t0[i], acc[i]);
    }
    if (BR) {
#pragma unroll
        for (int i = 0; i < 16; i++) acc[i] = fmaxf(acc[i] + bias[base + i], 0.f);
    }
    *(uint4*)(O + (size_t)node * D + base) = enc16(acc);
}

// MFMA GEMM: C[M,N] = A[M,K] @ B^T; A is fp8 [M,K] (decoded to f16 in LDS
// staging), B is [Npad,K] f16. 128x128 tile, 256 threads (2x2 waves of 64x64),
// 16x16x32 f16 MFMA. LDS row stride 40 elems to break 8-way bank aliasing.
// EPI: 0 = fp8 store, 1 = bias+relu fp8 store, 2 = bias+relu+column-mean atomic.
template <int EPI>
__global__ __launch_bounds__(256) void gemm_kernel(
    const unsigned char* __restrict__ A, const _Float16* __restrict__ B,
    const float* __restrict__ bias, unsigned char* __restrict__ Cb,
    float* __restrict__ outmean, int M, int K, int N) {
    __shared__ _Float16 Asl[128 * 40];
    __shared__ _Float16 Bsl[128 * 40];
    __shared__ float red[128];
    const int m0 = blockIdx.y * 128;
    const int n0 = blockIdx.x * 128;
    const int t = threadIdx.x;
    const int lane = t & 63, w = t >> 6;
    const int wm = (w >> 1) * 64, wn = (w & 1) * 64;
    const int r16 = lane & 15, quad = lane >> 4;

    floatx4 acc[4][4];
    const floatx4 fz = {0.f, 0.f, 0.f, 0.f};
#pragma unroll
    for (int i = 0; i < 4; i++)
#pragma unroll
        for (int j = 0; j < 4; j++) acc[i][j] = fz;

    for (int kc = 0; kc < K; kc += 32) {
        __syncthreads();
#pragma unroll
        for (int i = 0; i < 2; i++) {
            int seg = t + 256 * i;
            int row = seg >> 2, k8 = (seg & 3) * 8;
            int gm = m0 + row;
            if (gm > M - 1) gm = M - 1;
            uint2 av = *(const uint2*)(A + (size_t)gm * K + kc + k8);
            *(uint4*)(Asl + row * 40 + k8) = dec8_f16(av);
            int gn = n0 + row;  // B padded to Npad multiple of 128
            *(uint4*)(Bsl + row * 40 + k8) = *(const uint4*)(B + (size_t)gn * K + kc + k8);
        }
        __syncthreads();
        f16x8 af[4], bf[4];
#pragma unroll
        for (int i = 0; i < 4; i++)
            af[i] = *(const f16x8*)(Asl + (wm + i * 16 + r16) * 40 + quad * 8);
#pragma unroll
        for (int j = 0; j < 4; j++)
            bf[j] = *(const f16x8*)(Bsl + (wn + j * 16 + r16) * 40 + quad * 8);
#pragma unroll
        for (int i = 0; i < 4; i++)
#pragma unroll
            for (int j = 0; j < 4; j++)
                acc[i][j] = __builtin_amdgcn_mfma_f32_16x16x32_f16(af[i], bf[j], acc[i][j], 0, 0, 0);
    }

    if (EPI == 2) {
        if (t < 128) red[t] = 0.f;
        __syncthreads();
#pragma unroll
        for (int j = 0; j < 4; j++) {
            int col = n0 + wn + j * 16 + r16;
            float s = 0.f;
            if (col < N) {
                float bv = bias[col];
#pragma unroll
                for (int i = 0; i < 4; i++)
#pragma unroll
                    for (int r = 0; r < 4; r++) {
                        int m = m0 + wm + i * 16 + quad * 4 + r;
                        if (m < M) s += fmaxf(acc[i][j][r] + bv, 0.f);
                    }
            }
            atomicAdd(&red[wn + j * 16 + r16], s);
        }
        __syncthreads();
        if (t < 128) {
            int col = n0 + t;
            if (col < N) atomicAdd(outmean + col, red[t] * (1.0f / (float)NN));
        }
    } else {
#pragma unroll
        for (int i = 0; i < 4; i++)
#pragma unroll
            for (int r = 0; r < 4; r++) {
                int m = m0 + wm + i * 16 + quad * 4 + r;
                if (m >= M) continue;
#pragma unroll
                for (int j = 0; j < 4; j++) {
                    int col = n0 + wn + j * 16 + r16;
                    float v = acc[i][j][r];
                    if (EPI == 1) v = fmaxf(v + bias[col], 0.f);
                    unsigned pk = __builtin_amdgcn_cvt_pk_fp8_f32(v, v, 0, false);
                    Cb[(size_t)m * N + col] = (unsigned char)(pk & 0xffu);
                }
            }
    }
}

extern "C" void kernel_launch(void* const* d_in, const int* in_sizes, int n_in,
                              void* d_out, int out_size, void* d_ws, size_t ws_size,
                              hipStream_t stream) {
    const float* x  = (const float*)d_in[0];
    const void*  ei = d_in[1];
    const float* W1 = (const float*)d_in[2];
    const float* b1 = (const float*)d_in[3];
    const float* W2 = (const float*)d_in[4];
    const float* b2 = (const float*)d_in[5];
    const float* W3 = (const float*)d_in[6];
    const float* b3 = (const float*)d_in[7];
    const float* W4 = (const float*)d_in[8];
    const float* b4 = (const float*)d_in[9];
    float* out = (float*)d_out;

    char* ws = (char*)d_ws;
    size_t o = 0;
    auto alloc = [&](size_t bytes) -> void* {
        void* p = ws + o;
        o += (bytes + 255) & ~(size_t)255;
        return p;
    };
    int*      flag  = (int*)alloc(4);
    unsigned* cnt   = (unsigned*)alloc((size_t)NN * 4);
    int*      off   = (int*)alloc((size_t)(NN + 1) * 4);
    unsigned* fillc = (unsigned*)alloc((size_t)NN * 4);
    float*    dinv  = (float*)alloc((size_t)NN * 4);
    int*      ep    = (int*)alloc((size_t)NE * 4);
    _Float16* w1t = (_Float16*)alloc((size_t)512 * 128 * 2);
    _Float16* w2t = (_Float16*)alloc((size_t)256 * 512 * 2);
    _Float16* w3t = (_Float16*)alloc((size_t)128 * 256 * 2);
    _Float16* w4t = (_Float16*)alloc((size_t)256 * 128 * 2);
    int*      bsum  = (int*)alloc(256);
    // all activation buffers fp8 e4m3
    unsigned char* xb  = (unsigned char*)alloc((size_t)NN * 128);
    unsigned char* A1b = (unsigned char*)alloc((size_t)NN * 128);
    unsigned char* H1b = (unsigned char*)alloc((size_t)NN * 512);
    unsigned char* t2b = (unsigned char*)alloc((size_t)NN * 256);
    unsigned char* H2b = (unsigned char*)alloc((size_t)NN * 256);
    unsigned char* t3b = (unsigned char*)alloc((size_t)NN * 128);
    unsigned char* h3b = (unsigned char*)alloc((size_t)NN * 128);
    unsigned char* A4b = (unsigned char*)alloc((size_t)NN * 128);

    const int NB1 = (NN + 1023) / 1024;  // 49
    const int ZB = (NN + 255) / 256;     // 196
    const int PB = 1024;                 // partitioned CSR kernels: 128 groups x 8

    zero_detect_kernel<<<ZB, 256, 0, stream>>>((const unsigned*)ei, flag, cnt, fillc, out);
    count_kernel<<<PB, 256, 0, stream>>>(ei, flag, cnt);
    scan1_kernel<<<NB1, 256, 0, stream>>>(cnt, off, bsum, dinv);
    scan2_kernel<<<1, 64, 0, stream>>>(bsum, NB1);
    scan3_kernel<<<NB1, 256, 0, stream>>>(off, bsum);
    fill_kernel<<<PB, 256, 0, stream>>>(ei, flag, off, fillc, ep);
    xwcast_kernel<<<1563 + 1024, 256, 0, stream>>>(x, xb, W1, W2, W3, W4, w1t, w2t, w3t, w4t);

    const int MB = (NN + 127) / 128;         // 391
    const int AB128 = (NN * 8 + 255) / 256;  // 1563 (D=128: 8 lanes/node)
    const int AB256 = (NN * 16 + 255) / 256; // 3125 (D=256: 16 lanes/node)

    // L1: agg(xb) -> A1; gemm + bias + relu -> H1 [NN,512]
    agg_kernel<128, 0><<<AB128, 256, 0, stream>>>(xb, off, ep, dinv, nullptr, A1b);
    gemm_kernel<1><<<dim3(4, MB), 256, 0, stream>>>(A1b, w1t, b1, H1b, nullptr, NN, 128, 512);
    // L2: gemm H1 -> t2 [NN,256]; agg + bias + relu -> H2
    gemm_kernel<0><<<dim3(2, MB), 256, 0, stream>>>(H1b, w2t, nullptr, t2b, nullptr, NN, 512, 256);
    agg_kernel<256, 1><<<AB256, 256, 0, stream>>>(t2b, off, ep, dinv, b2, H2b);
    // L3: gemm H2 -> t3 [NN,128]; agg + bias + relu -> h3
    gemm_kernel<0><<<dim3(1, MB), 256, 0, stream>>>(H2b, w3t, nullptr, t3b, nullptr, NN, 256, 128);
    agg_kernel<128, 1><<<AB128, 256, 0, stream>>>(t3b, off, ep, dinv, b3, h3b);
    // L4: agg(h3) -> A4; gemm + bias + relu + fused column mean -> out
    agg_kernel<128, 0><<<AB128, 256, 0, stream>>>(h3b, off, ep, dinv, nullptr, A4b);
    gemm_kernel<2><<<dim3(2, MB), 256, 0, stream>>>(A4b, w4t, b4, nullptr, out, NN, 128, 200);
}

// Round 9
// 351.146 us; speedup vs baseline: 1.0148x; 1.0088x over previous
//
#include <hip/hip_runtime.h>
#include <hip/hip_bf16.h>

// GCN 4-layer, N=50000, E=800000, dims 100->512->256->128->200.
// f16 MFMA GEMMs: 64m x 128n tile (2x grid vs r8 -> occupancy), LDS stride 36
// (conflict-free b128), register-prefetch K-pipeline. All activations fp8 e4m3,
// weights f16, fp32 accumulate. CSR build XCD-partitioned.

#define NN 50000
#define NE 800000
#define NPART 8
#define PRANGE (NN / NPART)  // 6250

typedef __attribute__((ext_vector_type(8))) _Float16 f16x8;
typedef __attribute__((ext_vector_type(4))) float floatx4;
typedef __attribute__((ext_vector_type(2))) float floatx2;

union U16x8 {
    uint4 u4;
    f16x8 h;
    _Float16 e[8];
};

// decode 16 fp8 (16 B) -> 16 fp32 via HW cvt
__device__ __forceinline__ void dec16(const unsigned char* p, float* f) {
    uint4 v = *(const uint4*)p;
    unsigned w[4] = {v.x, v.y, v.z, v.w};
#pragma unroll
    for (int k = 0; k < 4; k++) {
        floatx2 lo = __builtin_amdgcn_cvt_pk_f32_fp8(w[k], false);
        floatx2 hi = __builtin_amdgcn_cvt_pk_f32_fp8(w[k], true);
        f[k * 4 + 0] = lo[0];
        f[k * 4 + 1] = lo[1];
        f[k * 4 + 2] = hi[0];
        f[k * 4 + 3] = hi[1];
    }
}

// encode 16 fp32 -> 16 fp8 (16 B)
__device__ __forceinline__ uint4 enc16(const float* f) {
    uint4 r;
    unsigned w;
    w = __builtin_amdgcn_cvt_pk_fp8_f32(f[0], f[1], 0, false);
    w = __builtin_amdgcn_cvt_pk_fp8_f32(f[2], f[3], (int)w, true);
    r.x = w;
    w = __builtin_amdgcn_cvt_pk_fp8_f32(f[4], f[5], 0, false);
    w = __builtin_amdgcn_cvt_pk_fp8_f32(f[6], f[7], (int)w, true);
    r.y = w;
    w = __builtin_amdgcn_cvt_pk_fp8_f32(f[8], f[9], 0, false);
    w = __builtin_amdgcn_cvt_pk_fp8_f32(f[10], f[11], (int)w, true);
    r.z = w;
    w = __builtin_amdgcn_cvt_pk_fp8_f32(f[12], f[13], 0, false);
    w = __builtin_amdgcn_cvt_pk_fp8_f32(f[14], f[15], (int)w, true);
    r.w = w;
    return r;
}

// decode 8 fp8 (8 B) -> 8 f16
__device__ __forceinline__ uint4 dec8_f16(uint2 v) {
    floatx2 f0 = __builtin_amdgcn_cvt_pk_f32_fp8(v.x, false);
    floatx2 f1 = __builtin_amdgcn_cvt_pk_f32_fp8(v.x, true);
    floatx2 f2 = __builtin_amdgcn_cvt_pk_f32_fp8(v.y, false);
    floatx2 f3 = __builtin_amdgcn_cvt_pk_f32_fp8(v.y, true);
    U16x8 o;
    o.e[0] = (_Float16)f0[0]; o.e[1] = (_Float16)f0[1];
    o.e[2] = (_Float16)f1[0]; o.e[3] = (_Float16)f1[1];
    o.e[4] = (_Float16)f2[0]; o.e[5] = (_Float16)f2[1];
    o.e[6] = (_Float16)f3[0]; o.e[7] = (_Float16)f3[1];
    return o.u4;
}

// ---------------- fused zero + dtype-detect ----------------
__global__ __launch_bounds__(256) void zero_detect_kernel(
    const unsigned* __restrict__ ei, int* __restrict__ flag,
    unsigned* __restrict__ cnt, unsigned* __restrict__ fillc,
    float* __restrict__ out) {
    int tid = blockIdx.x * 256 + threadIdx.x;
    if (tid < NN) {
        cnt[tid] = 0u;
        fillc[tid] = 0u;
    }
    if (blockIdx.x == 0) {
        if (threadIdx.x < 200) out[threadIdx.x] = 0.f;
        // int64 little-endian values < 2^31 => every odd 32-bit word == 0
        unsigned w = ei[2 * threadIdx.x + 1];
        unsigned long long any = __ballot(w != 0);
        if (threadIdx.x == 0) *flag = (any == 0ull) ? 1 : 0;
    }
}

// XCD-partitioned count: partition (blockIdx&7) owns c in [p*6250,(p+1)*6250).
__global__ __launch_bounds__(256) void count_kernel(const void* ei,
                                                    const int* __restrict__ flag,
                                                    unsigned* __restrict__ cnt) {
    const int part = blockIdx.x & 7;
    const int lo = part * PRANGE, hi = lo + PRANGE;
    const int group = blockIdx.x >> 3;           // 0..127
    const int f64 = *flag;
    const long long* p64 = (const long long*)ei + NE;
    const int* p32 = (const int*)ei + NE;
    for (int e = group * 256 + threadIdx.x; e < NE; e += 128 * 256) {
        int c = f64 ? (int)p64[e] : p32[e];
        if (c >= lo && c < hi) atomicAdd(&cnt[c], 1u);
    }
}

// hierarchical scan step 1 (49 blocks x 1024 elems) + fused dinv
__global__ __launch_bounds__(256) void scan1_kernel(const unsigned* __restrict__ cnt,
                                                    int* __restrict__ off,
                                                    int* __restrict__ bsum,
                                                    float* __restrict__ dinv) {
    __shared__ int ws[4];
    int b = blockIdx.x, t = threadIdx.x;
    int base = b * 1024 + t * 4;
    int v[4];
    int s = 0;
#pragma unroll
    for (int i = 0; i < 4; i++) {
        int val = 0;
        if (base + i < NN) {
            val = (int)cnt[base + i];
            dinv[base + i] = rsqrtf((float)(val + 1));
        }
        v[i] = s;
        s += val;
    }
    int lane = t & 63, wv = t >> 6;
    int x = s;
    for (int d = 1; d < 64; d <<= 1) {
        int y = __shfl_up(x, d, 64);
        if (lane >= d) x += y;
    }
    if (lane == 63) ws[wv] = x;
    __syncthreads();
    int wpre = 0;
#pragma unroll
    for (int i = 0; i < 4; i++)
        if (i < wv) wpre += ws[i];
    int texcl = x - s + wpre;
#pragma unroll
    for (int i = 0; i < 4; i++)
        if (base + i < NN) off[base + i] = texcl + v[i];
    if (t == 255) bsum[b] = texcl + s;
}

__global__ void scan2_kernel(int* bsum, int nb) {
    int t = threadIdx.x;
    int v = (t < nb) ? bsum[t] : 0;
    int x = v;
    for (int d = 1; d < 64; d <<= 1) {
        int y = __shfl_up(x, d, 64);
        if (t >= d) x += y;
    }
    if (t < nb) bsum[t] = x - v;
}

__global__ __launch_bounds__(256) void scan3_kernel(int* __restrict__ off,
                                                    const int* __restrict__ bsum) {
    int b = blockIdx.x;
    int add = bsum[b];
    int base = b * 1024 + threadIdx.x * 4;
#pragma unroll
    for (int i = 0; i < 4; i++)
        if (base + i < NN) off[base + i] += add;
    if (b == 0 && threadIdx.x == 0) off[NN] = NE;
}

// XCD-partitioned fill: ep[pos] = src row (4B). norm recomputed in agg.
__global__ __launch_bounds__(256) void fill_kernel(
    const void* ei, const int* __restrict__ flag, const int* __restrict__ off,
    unsigned* __restrict__ fillc, int* __restrict__ ep) {
    const int part = blockIdx.x & 7;
    const int lo = part * PRANGE, hi = lo + PRANGE;
    const int group = blockIdx.x >> 3;
    const int f64 = *flag;
    const long long* p64 = (const long long*)ei;
    const int* p32 = (const int*)ei;
    for (int e = group * 256 + threadIdx.x; e < NE; e += 128 * 256) {
        int c = f64 ? (int)p64[NE + e] : p32[NE + e];
        if (c >= lo && c < hi) {
            int r = f64 ? (int)p64[e] : p32[e];
            int pos = off[c] + (int)atomicAdd(&fillc[c], 1u);
            ep[pos] = r;
        }
    }
}

// fused: x fp32 [NN,100] -> fp8 [NN,128] zero-padded (blocks 0..1562)
//      + all 4 weights W [K,N] fp32 -> Wt [Npad,Kpad] f16 (blocks 1563..2586)
__global__ __launch_bounds__(256) void xwcast_kernel(
    const float* __restrict__ x, unsigned char* __restrict__ xb,
    const float* __restrict__ W1, const float* __restrict__ W2,
    const float* __restrict__ W3, const float* __restrict__ W4,
    _Float16* __restrict__ w1t, _Float16* __restrict__ w2t,
    _Float16* __restrict__ w3t, _Float16* __restrict__ w4t) {
    int bx = blockIdx.x, t = threadIdx.x;
    if (bx < 1563) {
        int tid = bx * 256 + t;
        int node = tid >> 3, sub = tid & 7;
        if (node >= NN) return;
        int base = sub * 16;
        float f[16];
#pragma unroll
        for (int i = 0; i < 16; i++) {
            int c = base + i;
            f[i] = (c < 100) ? x[(size_t)node * 100 + c] : 0.f;
        }
        *(uint4*)(xb + (size_t)node * 128 + base) = enc16(f);
        return;
    }
    int b = bx - 1563;
    const float* W;
    _Float16* Wt;
    int K, N, Kpad, tid;
    if (b < 256)      { W = W1; Wt = w1t; K = 100; N = 512; Kpad = 128; tid = b * 256 + t; }
    else if (b < 768) { W = W2; Wt = w2t; K = 512; N = 256; Kpad = 512; tid = (b - 256) * 256 + t; }
    else if (b < 896) { W = W3; Wt = w3t; K = 256; N = 128; Kpad = 256; tid = (b - 768) * 256 + t; }
    else              { W = W4; Wt = w4t; K = 128; N = 200; Kpad = 128; tid = (b - 896) * 256 + t; }
    int n = tid / Kpad, k = tid - n * Kpad;
    float v = (k < K && n < N) ? W[(size_t)k * N + n] : 0.f;
    Wt[tid] = (_Float16)v;
}

// aggregation: fp8 gathers + fp8 output, fp32 accumulate.
// D/16 lanes per node (16 feat/lane). norm = dinv[r]*dinv[c] recomputed.
template <int D, int BR>
__global__ __launch_bounds__(256) void agg_kernel(
    const unsigned char* __restrict__ H, const int* __restrict__ off,
    const int* __restrict__ ep, const float* __restrict__ dinv,
    const float* __restrict__ bias, unsigned char* __restrict__ O) {
    constexpr int LPN = D / 16;
    int tid = blockIdx.x * 256 + threadIdx.x;
    int node = tid / LPN;
    int sub = tid % LPN;
    if (node >= NN) return;
    int s = off[node], e = off[node + 1];
    float dc = dinv[node];
    float selfw = dc * dc;
    const int base = sub * 16;
    const unsigned char* __restrict__ Hb = H + base;
    float acc[16], t0[16], t1[16];
    dec16(Hb + (size_t)node * D, t0);
#pragma unroll
    for (int i = 0; i < 16; i++) acc[i] = selfw * t0[i];
    int j = s;
    for (; j + 2 <= e; j += 2) {
        int r0 = ep[j];
        int r1 = ep[j + 1];
        float w0 = dinv[r0] * dc;
        float w1 = dinv[r1] * dc;
        dec16(Hb + (size_t)r0 * D, t0);
        dec16(Hb + (size_t)r1 * D, t1);
#pragma unroll
        for (int i = 0; i < 16; i++) acc[i] = fmaf(w0, t0[i], acc[i]);
#pragma unroll
        for (int i = 0; i < 16; i++) acc[i] = fmaf(w1, t1[i], acc[i]);
    }
    if (j < e) {
        int r0 = ep[j];
        float w0 = dinv[r0] * dc;
        dec16(Hb + (size_t)r0 * D, t0);
#pragma unroll
        for (int i = 0; i < 16; i++) acc[i] = fmaf(w0, t0[i], acc[i]);
    }
    if (BR) {
#pragma unroll
        for (int i = 0; i < 16; i++) acc[i] = fmaxf(acc[i] + bias[base + i], 0.f);
    }
    *(uint4*)(O + (size_t)node * D + base) = enc16(acc);
}

// MFMA GEMM: C[M,N] = A[M,K] @ B^T; A fp8 [M,K] (decode in staging),
// B [Npad,K] f16. Tile 64m x 128n, 256 threads (2x2 waves: wm in {0,32},
// wn in {0,64}); BK=32; LDS row stride 36 elems (18 banks: conflict-free
// b128 across 16 rows); register-prefetch K-pipeline.
// EPI: 0 = fp8 store, 1 = bias+relu fp8 store, 2 = bias+relu+column-mean atomic.
template <int EPI>
__global__ __launch_bounds__(256) void gemm_kernel(
    const unsigned char* __restrict__ A, const _Float16* __restrict__ B,
    const float* __restrict__ bias, unsigned char* __restrict__ Cb,
    float* __restrict__ outmean, int M, int K, int N) {
    __shared__ _Float16 Asl[64 * 36];
    __shared__ _Float16 Bsl[128 * 36];
    __shared__ float red[128];
    const int m0 = blockIdx.y * 64;
    const int n0 = blockIdx.x * 128;
    const int t = threadIdx.x;
    const int lane = t & 63, w = t >> 6;
    const int wm = (w >> 1) * 32, wn = (w & 1) * 64;
    const int r16 = lane & 15, quad = lane >> 4;

    // staging addresses (fixed per thread)
    const int arow = t >> 2, ac8 = (t & 3) * 8;          // A: 64 rows x 4 chunks
    int gma = m0 + arow; if (gma > M - 1) gma = M - 1;
    const unsigned char* Aptr = A + (size_t)gma * K + ac8;
    const int brow0 = t >> 1, bc8_0 = (t & 1) * 8;       // B chunks 0..255
    const int brow1 = 128 + (t >> 1), bc8_1 = bc8_0;     // B chunks 256..511
    // B tile is 128 rows x 32 cols = 512 8-elem chunks; map: chunk c -> row c>>2, col (c&3)*8
    const int cb0 = t, cb1 = t + 256;
    const int rb0 = cb0 >> 2, kb0 = (cb0 & 3) * 8;
    const int rb1 = cb1 >> 2, kb1 = (cb1 & 3) * 8;
    const _Float16* Bptr0 = B + (size_t)(n0 + rb0) * K + kb0;
    const _Float16* Bptr1 = B + (size_t)(n0 + rb1) * K + kb1;

    floatx4 acc[2][4];
    const floatx4 fz = {0.f, 0.f, 0.f, 0.f};
#pragma unroll
    for (int i = 0; i < 2; i++)
#pragma unroll
        for (int j = 0; j < 4; j++) acc[i][j] = fz;

    uint2 apf = *(const uint2*)Aptr;
    uint4 bpf0 = *(const uint4*)Bptr0;
    uint4 bpf1 = *(const uint4*)Bptr1;

    for (int kc = 0; kc < K; kc += 32) {
        __syncthreads();  // previous iter's fragment reads done
        *(uint4*)(Asl + arow * 36 + ac8) = dec8_f16(apf);
        *(uint4*)(Bsl + rb0 * 36 + kb0) = bpf0;
        *(uint4*)(Bsl + rb1 * 36 + kb1) = bpf1;
        __syncthreads();
        if (kc + 32 < K) {  // issue next iter's global loads early
            apf = *(const uint2*)(Aptr + kc + 32);
            bpf0 = *(const uint4*)(Bptr0 + kc + 32);
            bpf1 = *(const uint4*)(Bptr1 + kc + 32);
        }
        f16x8 af[2], bf[4];
#pragma unroll
        for (int i = 0; i < 2; i++)
            af[i] = *(const f16x8*)(Asl + (wm + i * 16 + r16) * 36 + quad * 8);
#pragma unroll
        for (int j = 0; j < 4; j++)
            bf[j] = *(const f16x8*)(Bsl + (wn + j * 16 + r16) * 36 + quad * 8);
#pragma unroll
        for (int i = 0; i < 2; i++)
#pragma unroll
            for (int j = 0; j < 4; j++)
                acc[i][j] = __builtin_amdgcn_mfma_f32_16x16x32_f16(af[i], bf[j], acc[i][j], 0, 0, 0);
    }

    if (EPI == 2) {
        if (t < 128) red[t] = 0.f;
        __syncthreads();
#pragma unroll
        for (int j = 0; j < 4; j++) {
            int col = n0 + wn + j * 16 + r16;
            float s = 0.f;
            if (col < N) {
                float bv = bias[col];
#pragma unroll
                for (int i = 0; i < 2; i++) {
                    int mbase = m0 + wm + i * 16 + quad * 4;
#pragma unroll
                    for (int r = 0; r < 4; r++)
                        if (mbase + r < M) s += fmaxf(acc[i][j][r] + bv, 0.f);
                }
            }
            atomicAdd(&red[wn + j * 16 + r16], s);
        }
        __syncthreads();
        if (t < 128) {
            int col = n0 + t;
            if (col < N) atomicAdd(outmean + col, red[t] * (1.0f / (float)NN));
        }
    } else {
#pragma unroll
        for (int i = 0; i < 2; i++) {
            int mbase = m0 + wm + i * 16 + quad * 4;
#pragma unroll
            for (int r = 0; r < 4; r++) {
                int m = mbase + r;
                if (m >= M) continue;
#pragma unroll
                for (int j = 0; j < 4; j++) {
                    int col = n0 + wn + j * 16 + r16;
                    float v = acc[i][j][r];
                    if (EPI == 1) v = fmaxf(v + bias[col], 0.f);
                    unsigned pk = __builtin_amdgcn_cvt_pk_fp8_f32(v, v, 0, false);
                    Cb[(size_t)m * N + col] = (unsigned char)(pk & 0xffu);
                }
            }
        }
    }
}

extern "C" void kernel_launch(void* const* d_in, const int* in_sizes, int n_in,
                              void* d_out, int out_size, void* d_ws, size_t ws_size,
                              hipStream_t stream) {
    const float* x  = (const float*)d_in[0];
    const void*  ei = d_in[1];
    const float* W1 = (const float*)d_in[2];
    const float* b1 = (const float*)d_in[3];
    const float* W2 = (const float*)d_in[4];
    const float* b2 = (const float*)d_in[5];
    const float* W3 = (const float*)d_in[6];
    const float* b3 = (const float*)d_in[7];
    const float* W4 = (const float*)d_in[8];
    const float* b4 = (const float*)d_in[9];
    float* out = (float*)d_out;

    char* ws = (char*)d_ws;
    size_t o = 0;
    auto alloc = [&](size_t bytes) -> void* {
        void* p = ws + o;
        o += (bytes + 255) & ~(size_t)255;
        return p;
    };
    int*      flag  = (int*)alloc(4);
    unsigned* cnt   = (unsigned*)alloc((size_t)NN * 4);
    int*      off   = (int*)alloc((size_t)(NN + 1) * 4);
    unsigned* fillc = (unsigned*)alloc((size_t)NN * 4);
    float*    dinv  = (float*)alloc((size_t)NN * 4);
    int*      ep    = (int*)alloc((size_t)NE * 4);
    _Float16* w1t = (_Float16*)alloc((size_t)512 * 128 * 2);
    _Float16* w2t = (_Float16*)alloc((size_t)256 * 512 * 2);
    _Float16* w3t = (_Float16*)alloc((size_t)128 * 256 * 2);
    _Float16* w4t = (_Float16*)alloc((size_t)256 * 128 * 2);
    int*      bsum  = (int*)alloc(256);
    // all activation buffers fp8 e4m3
    unsigned char* xb  = (unsigned char*)alloc((size_t)NN * 128);
    unsigned char* A1b = (unsigned char*)alloc((size_t)NN * 128);
    unsigned char* H1b = (unsigned char*)alloc((size_t)NN * 512);
    unsigned char* t2b = (unsigned char*)alloc((size_t)NN * 256);
    unsigned char* H2b = (unsigned char*)alloc((size_t)NN * 256);
    unsigned char* t3b = (unsigned char*)alloc((size_t)NN * 128);
    unsigned char* h3b = (unsigned char*)alloc((size_t)NN * 128);
    unsigned char* A4b = (unsigned char*)alloc((size_t)NN * 128);

    const int NB1 = (NN + 1023) / 1024;  // 49
    const int ZB = (NN + 255) / 256;     // 196
    const int PB = 1024;                 // partitioned CSR kernels: 128 groups x 8

    zero_detect_kernel<<<ZB, 256, 0, stream>>>((const unsigned*)ei, flag, cnt, fillc, out);
    count_kernel<<<PB, 256, 0, stream>>>(ei, flag, cnt);
    scan1_kernel<<<NB1, 256, 0, stream>>>(cnt, off, bsum, dinv);
    scan2_kernel<<<1, 64, 0, stream>>>(bsum, NB1);
    scan3_kernel<<<NB1, 256, 0, stream>>>(off, bsum);
    fill_kernel<<<PB, 256, 0, stream>>>(ei, flag, off, fillc, ep);
    xwcast_kernel<<<1563 + 1024, 256, 0, stream>>>(x, xb, W1, W2, W3, W4, w1t, w2t, w3t, w4t);

    const int MB64 = (NN + 63) / 64;         // 782 m-blocks
    const int AB128 = (NN * 8 + 255) / 256;  // 1563 (D=128: 8 lanes/node)
    const int AB256 = (NN * 16 + 255) / 256; // 3125 (D=256: 16 lanes/node)

    // L1: agg(xb) -> A1; gemm + bias + relu -> H1 [NN,512]
    agg_kernel<128, 0><<<AB128, 256, 0, stream>>>(xb, off, ep, dinv, nullptr, A1b);
    gemm_kernel<1><<<dim3(4, MB64), 256, 0, stream>>>(A1b, w1t, b1, H1b, nullptr, NN, 128, 512);
    // L2: gemm H1 -> t2 [NN,256]; agg + bias + relu -> H2
    gemm_kernel<0><<<dim3(2, MB64), 256, 0, stream>>>(H1b, w2t, nullptr, t2b, nullptr, NN, 512, 256);
    agg_kernel<256, 1><<<AB256, 256, 0, stream>>>(t2b, off, ep, dinv, b2, H2b);
    // L3: gemm H2 -> t3 [NN,128]; agg + bias + relu -> h3
    gemm_kernel<0><<<dim3(1, MB64), 256, 0, stream>>>(H2b, w3t, nullptr, t3b, nullptr, NN, 256, 128);
    agg_kernel<128, 1><<<AB128, 256, 0, stream>>>(t3b, off, ep, dinv, b3, h3b);
    // L4: agg(h3) -> A4; gemm + bias + relu + fused column mean -> out
    agg_kernel<128, 0><<<AB128, 256, 0, stream>>>(h3b, off, ep, dinv, nullptr, A4b);
    gemm_kernel<2><<<dim3(2, MB64), 256, 0, stream>>>(A4b, w4t, b4, nullptr, out, NN, 128, 200);
}